// Round 1
// baseline (270.161 us; speedup 1.0000x reference)
//
#include <hip/hip_runtime.h>

typedef __bf16 bf16x8 __attribute__((ext_vector_type(8)));
typedef __bf16 bf16x4 __attribute__((ext_vector_type(4)));
typedef float  f32x4  __attribute__((ext_vector_type(4)));

#define B_   8
#define N_   4096
#define D_   256
#define TILE 128
#define BK   32

__device__ __forceinline__ void gl_lds16(const void* g, void* l) {
  __builtin_amdgcn_global_load_lds(
      (const __attribute__((address_space(1))) unsigned int*)g,
      (__attribute__((address_space(3))) unsigned int*)l, 16, 0, 0);
}

// One wave per point: fp32 -> bf16 convert, squared-norm of the *rounded*
// values (so P = ||x_hat - y_hat||^2 is exact in quantized space), and
// init rowmin/colmin to +inf.
__global__ __launch_bounds__(256) void prep_kernel(
    const float* __restrict__ x, const float* __restrict__ y,
    __bf16* __restrict__ Xb, __bf16* __restrict__ Yb,
    float* __restrict__ xx, float* __restrict__ yy,
    unsigned* __restrict__ rowmin, unsigned* __restrict__ colmin)
{
  int wid  = (blockIdx.x * 256 + threadIdx.x) >> 6;
  int lane = threadIdx.x & 63;
  const float* src; __bf16* dst; float* nrm; unsigned* mn; int p;
  if (wid < B_ * N_) { p = wid;            src = x; dst = Xb; nrm = xx; mn = rowmin; }
  else               { p = wid - B_ * N_;  src = y; dst = Yb; nrm = yy; mn = colmin; }

  float4 v = ((const float4*)(src + (size_t)p * D_))[lane];
  __bf16 b0 = (__bf16)v.x, b1 = (__bf16)v.y, b2 = (__bf16)v.z, b3 = (__bf16)v.w;
  bf16x4 st = {b0, b1, b2, b3};
  *((bf16x4*)(dst + (size_t)p * D_) + lane) = st;

  float f0 = (float)b0, f1 = (float)b1, f2 = (float)b2, f3 = (float)b3;
  float s = f0 * f0 + f1 * f1 + f2 * f2 + f3 * f3;
#pragma unroll
  for (int m = 1; m < 64; m <<= 1) s += __shfl_xor(s, m, 64);
  if (lane == 0) { nrm[p] = s; mn[p] = 0x7f800000u; }  // +inf as uint
}

// 128x128 tile per block, BK=32, 4 waves (2x2), 16x16x32 bf16 MFMA, 4x4
// accumulators per wave. global_load_lds width=16 staging (m97 structure).
// Epilogue: P = xx + yy - 2*zz; min along both axes; atomicMin (float-as-uint).
__global__ __launch_bounds__(256) void chamfer_gemm(
    const __bf16* __restrict__ Xb, const __bf16* __restrict__ Yb,
    const float* __restrict__ xx, const float* __restrict__ yy,
    unsigned* __restrict__ rowmin, unsigned* __restrict__ colmin)
{
  __shared__ __align__(16) __bf16 As[TILE * BK];
  __shared__ __align__(16) __bf16 Bs[TILE * BK];

  const int b    = blockIdx.z;
  const int n0   = blockIdx.y * TILE;
  const int m0   = blockIdx.x * TILE;
  const int t    = threadIdx.x;
  const int lane = t & 63;
  const int wave = t >> 6;
  const int wrow = wave >> 1, wcol = wave & 1;
  const int quad = lane >> 4, lcol = lane & 15;

  const __bf16* Xp = Xb + ((size_t)b * N_ + n0) * D_;
  const __bf16* Yp = Yb + ((size_t)b * N_ + m0) * D_;

  // staging map: segment s (0..511) -> row s>>2, k-col (s&3)*8; thread t
  // handles segments t and t+256; LDS dest = s*16 bytes (lane-order, required
  // by global_load_lds wave-uniform-base semantics).
  const int r0 = t >> 2;
  const int kc = (t & 3) * 8;

  f32x4 acc[4][4] = {};

  for (int kt = 0; kt < D_ / BK; ++kt) {
    const int k0 = kt * BK;
    __syncthreads();  // all waves done reading previous tile
    gl_lds16(Xp + (size_t)r0 * D_ + k0 + kc,        As + t * 8);
    gl_lds16(Xp + (size_t)(r0 + 64) * D_ + k0 + kc, As + t * 8 + 2048);
    gl_lds16(Yp + (size_t)r0 * D_ + k0 + kc,        Bs + t * 8);
    gl_lds16(Yp + (size_t)(r0 + 64) * D_ + k0 + kc, Bs + t * 8 + 2048);
    __syncthreads();  // compiler emits vmcnt(0) drain before barrier

    bf16x8 af[4], bfr[4];
#pragma unroll
    for (int i = 0; i < 4; ++i)
      af[i] = *(const bf16x8*)(As + (wrow * 64 + i * 16 + lcol) * BK + quad * 8);
#pragma unroll
    for (int j = 0; j < 4; ++j)
      bfr[j] = *(const bf16x8*)(Bs + (wcol * 64 + j * 16 + lcol) * BK + quad * 8);

#pragma unroll
    for (int i = 0; i < 4; ++i)
#pragma unroll
      for (int j = 0; j < 4; ++j)
        acc[i][j] = __builtin_amdgcn_mfma_f32_16x16x32_bf16(af[i], bfr[j], acc[i][j], 0, 0, 0);
  }

  // ---- epilogue ----
  // C/D layout (m89-verified): col = lane&15, row = quad*4 + reg.
  const float* xxp = xx + b * N_ + n0 + wrow * 64;
  const float* yyp = yy + b * N_ + m0 + wcol * 64;

  float xv[4][4], yv[4];
#pragma unroll
  for (int i = 0; i < 4; ++i)
#pragma unroll
    for (int r = 0; r < 4; ++r)
      xv[i][r] = xxp[i * 16 + quad * 4 + r];
#pragma unroll
  for (int j = 0; j < 4; ++j)
    yv[j] = yyp[j * 16 + lcol];

  unsigned* rmp = rowmin + b * N_ + n0 + wrow * 64;
  unsigned* cmp = colmin + b * N_ + m0 + wcol * 64;

  // rowmin[n] = min over m (loss_2 direction)
#pragma unroll
  for (int i = 0; i < 4; ++i) {
#pragma unroll
    for (int r = 0; r < 4; ++r) {
      float v = 1e30f;
#pragma unroll
      for (int j = 0; j < 4; ++j)
        v = fminf(v, xv[i][r] + yv[j] - 2.0f * acc[i][j][r]);
#pragma unroll
      for (int m = 1; m < 16; m <<= 1) v = fminf(v, __shfl_xor(v, m, 64));
      if (lcol == 0)
        atomicMin(rmp + i * 16 + quad * 4 + r, __float_as_uint(v));
    }
  }

  // colmin[m] = min over n (loss_1 direction)
#pragma unroll
  for (int j = 0; j < 4; ++j) {
    float v = 1e30f;
#pragma unroll
    for (int i = 0; i < 4; ++i)
#pragma unroll
      for (int r = 0; r < 4; ++r)
        v = fminf(v, xv[i][r] + yv[j] - 2.0f * acc[i][j][r]);
    v = fminf(v, __shfl_xor(v, 16, 64));
    v = fminf(v, __shfl_xor(v, 32, 64));
    if (quad == 0)
      atomicMin(cmp + j * 16 + lcol, __float_as_uint(v));
  }
}

__global__ __launch_bounds__(1024) void reduce_kernel(
    const unsigned* __restrict__ rowmin, const unsigned* __restrict__ colmin,
    float* __restrict__ out)
{
  __shared__ float part[16];
  float s = 0.f;
  for (int i = threadIdx.x; i < B_ * N_; i += 1024)
    s += __uint_as_float(rowmin[i]) + __uint_as_float(colmin[i]);
#pragma unroll
  for (int m = 1; m < 64; m <<= 1) s += __shfl_xor(s, m, 64);
  int lane = threadIdx.x & 63, w = threadIdx.x >> 6;
  if (lane == 0) part[w] = s;
  __syncthreads();
  if (w == 0) {
    float t2 = (lane < 16) ? part[lane] : 0.f;
#pragma unroll
    for (int m = 1; m < 16; m <<= 1) t2 += __shfl_xor(t2, m, 64);
    if (lane == 0) out[0] = t2;
  }
}

extern "C" void kernel_launch(void* const* d_in, const int* in_sizes, int n_in,
                              void* d_out, int out_size, void* d_ws, size_t ws_size,
                              hipStream_t stream) {
  const float* gts   = (const float*)d_in[0];   // [8,4096,256] fp32
  const float* preds = (const float*)d_in[1];   // [8,4096,256] fp32

  char* ws = (char*)d_ws;
  const size_t XB_BYTES = (size_t)B_ * N_ * D_ * 2;     // 16 MiB
  __bf16*   Xb     = (__bf16*)ws;
  __bf16*   Yb     = (__bf16*)(ws + XB_BYTES);
  float*    xx     = (float*)(ws + 2 * XB_BYTES);
  float*    yy     = (float*)(ws + 2 * XB_BYTES + (size_t)B_ * N_ * 4);
  unsigned* rowmin = (unsigned*)(ws + 2 * XB_BYTES + (size_t)B_ * N_ * 8);
  unsigned* colmin = (unsigned*)(ws + 2 * XB_BYTES + (size_t)B_ * N_ * 12);

  // 65536 points total, one wave each, 4 waves/block -> 16384 blocks
  prep_kernel<<<16384, 256, 0, stream>>>(gts, preds, Xb, Yb, xx, yy, rowmin, colmin);

  dim3 grid(N_ / TILE, N_ / TILE, B_);
  chamfer_gemm<<<grid, 256, 0, stream>>>(Xb, Yb, xx, yy, rowmin, colmin);

  reduce_kernel<<<1, 1024, 0, stream>>>(rowmin, colmin, (float*)d_out);
}

// Round 2
// 180.304 us; speedup vs baseline: 1.4984x; 1.4984x over previous
//
#include <hip/hip_runtime.h>

typedef __bf16 bf16x8 __attribute__((ext_vector_type(8)));
typedef __bf16 bf16x4 __attribute__((ext_vector_type(4)));
typedef float  f32x4  __attribute__((ext_vector_type(4)));

#define B_   8
#define N_   4096
#define D_   256
#define CT_  64      // col-tile width
#define NCT  16      // col-tiles per block (block covers 1024 cols)

__device__ __forceinline__ void gl_lds16(const void* g, void* l) {
  __builtin_amdgcn_global_load_lds(
      (const __attribute__((address_space(1))) unsigned int*)g,
      (__attribute__((address_space(3))) unsigned int*)l, 16, 0, 0);
}

// One wave per point: fp32 -> bf16 convert, squared-norm of the *rounded*
// values (P stays exact in quantized space), init rowmin/colmin to +inf.
__global__ __launch_bounds__(256) void prep_kernel(
    const float* __restrict__ x, const float* __restrict__ y,
    __bf16* __restrict__ Xb, __bf16* __restrict__ Yb,
    float* __restrict__ xx, float* __restrict__ yy,
    unsigned* __restrict__ rowmin, unsigned* __restrict__ colmin)
{
  int wid  = (blockIdx.x * 256 + threadIdx.x) >> 6;
  int lane = threadIdx.x & 63;
  const float* src; __bf16* dst; float* nrm; unsigned* mn; int p;
  if (wid < B_ * N_) { p = wid;            src = x; dst = Xb; nrm = xx; mn = rowmin; }
  else               { p = wid - B_ * N_;  src = y; dst = Yb; nrm = yy; mn = colmin; }

  float4 v = ((const float4*)(src + (size_t)p * D_))[lane];
  __bf16 b0 = (__bf16)v.x, b1 = (__bf16)v.y, b2 = (__bf16)v.z, b3 = (__bf16)v.w;
  bf16x4 st = {b0, b1, b2, b3};
  *((bf16x4*)(dst + (size_t)p * D_) + lane) = st;

  float f0 = (float)b0, f1 = (float)b1, f2 = (float)b2, f3 = (float)b3;
  float s = f0 * f0 + f1 * f1 + f2 * f2 + f3 * f3;
#pragma unroll
  for (int m = 1; m < 64; m <<= 1) s += __shfl_xor(s, m, 64);
  if (lane == 0) { nrm[p] = s; mn[p] = 0x7f800000u; }  // +inf as uint
}

// Persistent-A streaming-B chamfer GEMM.
// Block: 128 rows x 1024 cols (16 col-tiles of 64). 4 waves stacked in rows,
// wave tile 32x64 per col-tile, 16x16x32 bf16 MFMA (2x4 accs).
// A tile (128x256 = 64KB) staged once -> A fragments live in registers.
// B double-buffered (2x32KB), prefetch issued before compute so the barrier's
// vmcnt(0) drain is free. XOR-swizzled LDS layout -> 2-way bank aliasing.
__global__ __launch_bounds__(256, 2) void chamfer_gemm(
    const __bf16* __restrict__ Xb, const __bf16* __restrict__ Yb,
    const float* __restrict__ xx, const float* __restrict__ yy,
    unsigned* __restrict__ rowmin, unsigned* __restrict__ colmin)
{
  __shared__ __align__(16) __bf16 S[32768];        // 64 KB: A scratch, then B dbuf
  __shared__ unsigned cmin_s[NCT * CT_];            // 4 KB col-min table

  const int bid  = blockIdx.x;
  const int b    = bid & 7;                // batch == XCD (L2 locality)
  const int rt   = (bid >> 3) & 31;
  const int cq   = bid >> 8;               // 0..3
  const int n0   = rt * 128;
  const int m0   = cq * (NCT * CT_);

  const int t    = threadIdx.x;
  const int lane = t & 63;
  const int wave = t >> 6;
  const int quad = lane >> 4, lcol = lane & 15;

  const __bf16* Ap    = Xb + ((size_t)b * N_ + n0) * D_;
  const __bf16* Ybase = Yb + ((size_t)b * N_ + m0) * D_;

#pragma unroll
  for (int i = 0; i < 4; ++i) cmin_s[t + i * 256] = 0x7f800000u;

  // ---- stage A tile (128 rows x 256 K) into all 64 KB ----
  // chunk kt (8KB): slot(r,q') = r*4 + q', holds k8 q = q' ^ ((r>>1)&3)
#pragma unroll
  for (int kt = 0; kt < 8; ++kt)
#pragma unroll
    for (int h = 0; h < 2; ++h) {
      int s = t + h * 256;
      int r = s >> 2;
      int q = (s & 3) ^ ((r >> 1) & 3);
      gl_lds16(Ap + (size_t)r * D_ + kt * 32 + q * 8, S + kt * 4096 + s * 8);
    }
  __syncthreads();

  const int qsw = quad ^ ((lcol >> 1) & 3);

  // ---- A fragments -> registers (rows wave*32 + i*16 + lcol) ----
  bf16x8 af[8][2];
#pragma unroll
  for (int kt = 0; kt < 8; ++kt)
#pragma unroll
    for (int i = 0; i < 2; ++i) {
      int rr = wave * 32 + i * 16 + lcol;
      af[kt][i] = *(const bf16x8*)(S + kt * 4096 + rr * 32 + qsw * 8);
    }

  float xv[2][4], rmin[2][4];
  const float* xxp = xx + b * N_ + n0 + wave * 32;
#pragma unroll
  for (int i = 0; i < 2; ++i)
#pragma unroll
    for (int r = 0; r < 4; ++r) {
      xv[i][r] = xxp[i * 16 + quad * 4 + r];
      rmin[i][r] = 1e30f;
    }
  __syncthreads();   // everyone done reading A scratch

  // ---- prefetch B(0) into buf0 ----
  {
    int c = t >> 2;
    int q = (t & 3) ^ ((c >> 1) & 3);
#pragma unroll
    for (int kt = 0; kt < 8; ++kt)
      gl_lds16(Ybase + (size_t)c * D_ + kt * 32 + q * 8, S + kt * 2048 + t * 8);
  }

  for (int ct = 0; ct < NCT; ++ct) {
    __syncthreads();  // drains B(ct) prefetch (in flight during prior compute)
    __bf16* curb = S + (ct & 1) * 16384;
    if (ct + 1 < NCT) {
      const __bf16* Bp = Ybase + (size_t)(ct + 1) * CT_ * D_;
      __bf16* nb = S + ((ct + 1) & 1) * 16384;
      int c = t >> 2;
      int q = (t & 3) ^ ((c >> 1) & 3);
#pragma unroll
      for (int kt = 0; kt < 8; ++kt)
        gl_lds16(Bp + (size_t)c * D_ + kt * 32 + q * 8, nb + kt * 2048 + t * 8);
    }

    f32x4 acc[2][4] = {};
#pragma unroll
    for (int kt = 0; kt < 8; ++kt) {
      bf16x8 bf[4];
#pragma unroll
      for (int j = 0; j < 4; ++j) {
        int c = j * 16 + lcol;
        bf[j] = *(const bf16x8*)(curb + kt * 2048 + c * 32 + qsw * 8);
      }
#pragma unroll
      for (int i = 0; i < 2; ++i)
#pragma unroll
        for (int j = 0; j < 4; ++j)
          acc[i][j] = __builtin_amdgcn_mfma_f32_16x16x32_bf16(af[kt][i], bf[j], acc[i][j], 0, 0, 0);
    }

    // ---- epilogue: C/D layout row = i*16 + quad*4 + r, col = j*16 + lcol ----
    float yv[4];
#pragma unroll
    for (int j = 0; j < 4; ++j) yv[j] = yy[b * N_ + m0 + ct * CT_ + j * 16 + lcol];
#pragma unroll
    for (int j = 0; j < 4; ++j) {
      float cm = 1e30f;
#pragma unroll
      for (int i = 0; i < 2; ++i)
#pragma unroll
        for (int r = 0; r < 4; ++r) {
          float tz = -2.0f * acc[i][j][r];
          rmin[i][r] = fminf(rmin[i][r], tz + yv[j]);   // xv deferred
          cm = fminf(cm, tz + xv[i][r]);                // yv deferred
        }
      cm = fminf(cm, __shfl_xor(cm, 16, 64));
      cm = fminf(cm, __shfl_xor(cm, 32, 64));
      if (quad == 0)
        atomicMin(&cmin_s[ct * CT_ + j * 16 + lcol], __float_as_uint(cm + yv[j]));
    }
  }

  // ---- rowmin: finalize (once per block) ----
#pragma unroll
  for (int i = 0; i < 2; ++i)
#pragma unroll
    for (int r = 0; r < 4; ++r) {
      float v = xv[i][r] + rmin[i][r];
#pragma unroll
      for (int m = 1; m < 16; m <<= 1) v = fminf(v, __shfl_xor(v, m, 64));
      if (lcol == 0)
        atomicMin(rowmin + b * N_ + n0 + wave * 32 + i * 16 + quad * 4 + r,
                  __float_as_uint(v));
    }

  __syncthreads();
  // ---- colmin: flush LDS table to global ----
#pragma unroll
  for (int i = 0; i < 4; ++i) {
    int idx = t + i * 256;
    atomicMin(colmin + b * N_ + m0 + idx, cmin_s[idx]);
  }
}

__global__ __launch_bounds__(1024) void reduce_kernel(
    const unsigned* __restrict__ mins,   // rowmin then colmin, contiguous
    float* __restrict__ out)
{
  __shared__ float part[16];
  float s = 0.f;
  const uint4* p = (const uint4*)mins;
  for (int i = threadIdx.x; i < (2 * B_ * N_) / 4; i += 1024) {
    uint4 u = p[i];
    s += __uint_as_float(u.x) + __uint_as_float(u.y)
       + __uint_as_float(u.z) + __uint_as_float(u.w);
  }
#pragma unroll
  for (int m = 1; m < 64; m <<= 1) s += __shfl_xor(s, m, 64);
  int lane = threadIdx.x & 63, w = threadIdx.x >> 6;
  if (lane == 0) part[w] = s;
  __syncthreads();
  if (w == 0) {
    float t2 = (lane < 16) ? part[lane] : 0.f;
#pragma unroll
    for (int m = 1; m < 16; m <<= 1) t2 += __shfl_xor(t2, m, 64);
    if (lane == 0) out[0] = t2;
  }
}

extern "C" void kernel_launch(void* const* d_in, const int* in_sizes, int n_in,
                              void* d_out, int out_size, void* d_ws, size_t ws_size,
                              hipStream_t stream) {
  const float* gts   = (const float*)d_in[0];   // [8,4096,256] fp32
  const float* preds = (const float*)d_in[1];   // [8,4096,256] fp32

  char* ws = (char*)d_ws;
  const size_t XB_BYTES = (size_t)B_ * N_ * D_ * 2;     // 16 MiB
  __bf16*   Xb     = (__bf16*)ws;
  __bf16*   Yb     = (__bf16*)(ws + XB_BYTES);
  float*    xx     = (float*)(ws + 2 * XB_BYTES);
  float*    yy     = (float*)(ws + 2 * XB_BYTES + (size_t)B_ * N_ * 4);
  unsigned* rowmin = (unsigned*)(ws + 2 * XB_BYTES + (size_t)B_ * N_ * 8);
  unsigned* colmin = (unsigned*)(ws + 2 * XB_BYTES + (size_t)B_ * N_ * 12);

  prep_kernel<<<16384, 256, 0, stream>>>(gts, preds, Xb, Yb, xx, yy, rowmin, colmin);

  // 8 batches x 32 row-tiles x 4 col-quarters = 1024 blocks
  chamfer_gemm<<<1024, 256, 0, stream>>>(Xb, Yb, xx, yy, rowmin, colmin);

  reduce_kernel<<<1, 1024, 0, stream>>>(rowmin, (float*)d_out);
}

// Round 3
// 176.515 us; speedup vs baseline: 1.5305x; 1.0215x over previous
//
#include <hip/hip_runtime.h>

typedef __bf16 bf16x8 __attribute__((ext_vector_type(8)));
typedef __bf16 bf16x4 __attribute__((ext_vector_type(4)));
typedef float  f32x4  __attribute__((ext_vector_type(4)));

#define B_   8
#define N_   4096
#define D_   256
#define CT_  32      // col-tile width
#define NCT  32      // col-tiles per block (block covers 1024 cols)

__device__ __forceinline__ void gl_lds16(const void* g, void* l) {
  __builtin_amdgcn_global_load_lds(
      (const __attribute__((address_space(1))) unsigned int*)g,
      (__attribute__((address_space(3))) unsigned int*)l, 16, 0, 0);
}

// One wave per point: fp32 -> bf16 convert, squared-norm of the *rounded*
// values (P stays exact in quantized space), init rowmin/colmin to +inf.
__global__ __launch_bounds__(256) void prep_kernel(
    const float* __restrict__ x, const float* __restrict__ y,
    __bf16* __restrict__ Xb, __bf16* __restrict__ Yb,
    float* __restrict__ xx, float* __restrict__ yy,
    unsigned* __restrict__ rowmin, unsigned* __restrict__ colmin,
    float* __restrict__ out)
{
  if (blockIdx.x == 0 && threadIdx.x == 0) out[0] = 0.f;  // for reduce atomicAdd
  int wid  = (blockIdx.x * 256 + threadIdx.x) >> 6;
  int lane = threadIdx.x & 63;
  const float* src; __bf16* dst; float* nrm; unsigned* mn; int p;
  if (wid < B_ * N_) { p = wid;            src = x; dst = Xb; nrm = xx; mn = rowmin; }
  else               { p = wid - B_ * N_;  src = y; dst = Yb; nrm = yy; mn = colmin; }

  float4 v = ((const float4*)(src + (size_t)p * D_))[lane];
  __bf16 b0 = (__bf16)v.x, b1 = (__bf16)v.y, b2 = (__bf16)v.z, b3 = (__bf16)v.w;
  bf16x4 st = {b0, b1, b2, b3};
  *((bf16x4*)(dst + (size_t)p * D_) + lane) = st;

  float f0 = (float)b0, f1 = (float)b1, f2 = (float)b2, f3 = (float)b3;
  float s = f0 * f0 + f1 * f1 + f2 * f2 + f3 * f3;
#pragma unroll
  for (int m = 1; m < 64; m <<= 1) s += __shfl_xor(s, m, 64);
  if (lane == 0) { nrm[p] = s; mn[p] = 0x7f800000u; }  // +inf as uint
}

// Persistent-A streaming-B chamfer GEMM, occupancy-optimized.
// Block: 128 rows x 1024 cols (32 col-tiles of 32). 4 waves row-stacked,
// wave tile 32x32 per col-tile, 16x16x32 bf16 MFMA (2x2 accs).
// A tile staged in two 32KB halves through LDS region S, which is then
// reused as the B double-buffer (2x16KB) -> LDS 36KB -> 4 blocks/CU
// (16 waves/CU, 4 waves/SIMD vs round-2's 2). Zero-conflict swizzle kept.
__global__ __launch_bounds__(256, 4) void chamfer_gemm(
    const __bf16* __restrict__ Xb, const __bf16* __restrict__ Yb,
    const float* __restrict__ xx, const float* __restrict__ yy,
    unsigned* __restrict__ rowmin, unsigned* __restrict__ colmin)
{
  __shared__ __align__(16) __bf16 S[16384];   // 32 KB: A-half stage, then B dbuf
  __shared__ unsigned cmin_s[NCT * CT_];      // 4 KB col-min table

  const int bid  = blockIdx.x;
  const int b    = bid & 7;                // batch == XCD (L2 locality)
  const int rt   = (bid >> 3) & 31;
  const int cq   = bid >> 8;               // 0..3
  const int n0   = rt * 128;
  const int m0   = cq * (NCT * CT_);

  const int t    = threadIdx.x;
  const int lane = t & 63;
  const int wave = t >> 6;
  const int quad = lane >> 4, lcol = lane & 15;
  const int qsw  = quad ^ ((lcol >> 1) & 3);

  const __bf16* Ap    = Xb + ((size_t)b * N_ + n0) * D_;
  const __bf16* Ybase = Yb + ((size_t)b * N_ + m0) * D_;

#pragma unroll
  for (int i = 0; i < 4; ++i) cmin_s[t + i * 256] = 0x7f800000u;

  // ---- stage A tile (128 rows x 256 K) in two 32KB halves; frags -> regs ----
  // half layout: seg s = kt*512 + r*4 + q', q = q' ^ ((r>>1)&3), LDS at s*16B
  bf16x8 af[8][2];
#pragma unroll
  for (int half = 0; half < 2; ++half) {
    __syncthreads();   // (2nd iter) everyone done reading previous half
#pragma unroll
    for (int h = 0; h < 8; ++h) {
      int s = t + h * 256;
      int kt = s >> 9;
      int r  = (s >> 2) & 127;
      int q  = (s & 3) ^ ((r >> 1) & 3);
      gl_lds16(Ap + (size_t)r * D_ + half * 128 + kt * 32 + q * 8, S + s * 8);
    }
    __syncthreads();
#pragma unroll
    for (int kt = 0; kt < 4; ++kt)
#pragma unroll
      for (int i = 0; i < 2; ++i) {
        int rr = wave * 32 + i * 16 + lcol;
        af[half * 4 + kt][i] = *(const bf16x8*)(S + kt * 4096 + rr * 32 + qsw * 8);
      }
  }

  float xv[2][4], rmin[2][4];
  const float* xxp = xx + b * N_ + n0 + wave * 32;
#pragma unroll
  for (int i = 0; i < 2; ++i)
#pragma unroll
    for (int r = 0; r < 4; ++r) {
      xv[i][r] = xxp[i * 16 + quad * 4 + r];
      rmin[i][r] = 1e30f;
    }
  __syncthreads();   // everyone done reading A scratch

  // ---- prefetch B(0): seg s = kt*128 + c*4 + q', tile = 32 cols x 256 K ----
#pragma unroll
  for (int h = 0; h < 4; ++h) {
    int s = t + h * 256;
    int kt = s >> 7;
    int c  = (s >> 2) & 31;
    int q  = (s & 3) ^ ((c >> 1) & 3);
    gl_lds16(Ybase + (size_t)c * D_ + kt * 32 + q * 8, S + s * 8);
  }

  const float* yyp = yy + b * N_ + m0;

  for (int ct = 0; ct < NCT; ++ct) {
    __syncthreads();  // drains B(ct) prefetch (in flight during prior compute)
    const __bf16* curb = S + (ct & 1) * 8192;
    if (ct + 1 < NCT) {
      const __bf16* Bp = Ybase + (size_t)(ct + 1) * CT_ * D_;
      __bf16* nb = S + ((ct + 1) & 1) * 8192;
#pragma unroll
      for (int h = 0; h < 4; ++h) {
        int s = t + h * 256;
        int kt = s >> 7;
        int c  = (s >> 2) & 31;
        int q  = (s & 3) ^ ((c >> 1) & 3);
        gl_lds16(Bp + (size_t)c * D_ + kt * 32 + q * 8, nb + s * 8);
      }
    }
    // yv loads early: latency hides under the MFMA loop
    float yv0 = yyp[ct * CT_ + lcol];
    float yv1 = yyp[ct * CT_ + 16 + lcol];

    f32x4 acc[2][2] = {};
#pragma unroll
    for (int kt = 0; kt < 8; ++kt) {
      bf16x8 bf0 = *(const bf16x8*)(curb + kt * 1024 + lcol * 32 + qsw * 8);
      bf16x8 bf1 = *(const bf16x8*)(curb + kt * 1024 + (16 + lcol) * 32 + qsw * 8);
      acc[0][0] = __builtin_amdgcn_mfma_f32_16x16x32_bf16(af[kt][0], bf0, acc[0][0], 0, 0, 0);
      acc[0][1] = __builtin_amdgcn_mfma_f32_16x16x32_bf16(af[kt][0], bf1, acc[0][1], 0, 0, 0);
      acc[1][0] = __builtin_amdgcn_mfma_f32_16x16x32_bf16(af[kt][1], bf0, acc[1][0], 0, 0, 0);
      acc[1][1] = __builtin_amdgcn_mfma_f32_16x16x32_bf16(af[kt][1], bf1, acc[1][1], 0, 0, 0);
    }

    // ---- epilogue: row = i*16 + quad*4 + r, col = j*16 + lcol ----
#pragma unroll
    for (int j = 0; j < 2; ++j) {
      float yv = j ? yv1 : yv0;
      float cm = 1e30f;
#pragma unroll
      for (int i = 0; i < 2; ++i)
#pragma unroll
        for (int r = 0; r < 4; ++r) {
          float a = acc[i][j][r];
          rmin[i][r] = fminf(rmin[i][r], __builtin_fmaf(-2.0f, a, yv));
          cm         = fminf(cm,         __builtin_fmaf(-2.0f, a, xv[i][r]));
        }
      cm = fminf(cm, __shfl_xor(cm, 16, 64));
      cm = fminf(cm, __shfl_xor(cm, 32, 64));
      if (quad == 0)
        atomicMin(&cmin_s[ct * CT_ + j * 16 + lcol], __float_as_uint(cm + yv));
    }
  }

  // ---- rowmin: finalize (once per block) ----
#pragma unroll
  for (int i = 0; i < 2; ++i)
#pragma unroll
    for (int r = 0; r < 4; ++r) {
      float v = xv[i][r] + rmin[i][r];
#pragma unroll
      for (int m = 1; m < 16; m <<= 1) v = fminf(v, __shfl_xor(v, m, 64));
      if (lcol == 0)
        atomicMin(rowmin + b * N_ + n0 + wave * 32 + i * 16 + quad * 4 + r,
                  __float_as_uint(v));
    }

  __syncthreads();
  // ---- colmin: flush LDS table to global ----
#pragma unroll
  for (int i = 0; i < 4; ++i) {
    int idx = t + i * 256;
    atomicMin(colmin + b * N_ + m0 + idx, cmin_s[idx]);
  }
}

// 64 blocks x 256 threads: 16384 uint4 = 65536 mins; wave-reduce + atomicAdd.
__global__ __launch_bounds__(256) void reduce_kernel(
    const unsigned* __restrict__ mins,   // rowmin then colmin, contiguous
    float* __restrict__ out)
{
  int idx = blockIdx.x * 256 + threadIdx.x;
  uint4 u = ((const uint4*)mins)[idx];
  float s = __uint_as_float(u.x) + __uint_as_float(u.y)
          + __uint_as_float(u.z) + __uint_as_float(u.w);
#pragma unroll
  for (int m = 1; m < 64; m <<= 1) s += __shfl_xor(s, m, 64);
  if ((threadIdx.x & 63) == 0) atomicAdd(out, s);
}

extern "C" void kernel_launch(void* const* d_in, const int* in_sizes, int n_in,
                              void* d_out, int out_size, void* d_ws, size_t ws_size,
                              hipStream_t stream) {
  const float* gts   = (const float*)d_in[0];   // [8,4096,256] fp32
  const float* preds = (const float*)d_in[1];   // [8,4096,256] fp32

  char* ws = (char*)d_ws;
  const size_t XB_BYTES = (size_t)B_ * N_ * D_ * 2;     // 16 MiB
  __bf16*   Xb     = (__bf16*)ws;
  __bf16*   Yb     = (__bf16*)(ws + XB_BYTES);
  float*    xx     = (float*)(ws + 2 * XB_BYTES);
  float*    yy     = (float*)(ws + 2 * XB_BYTES + (size_t)B_ * N_ * 4);
  unsigned* rowmin = (unsigned*)(ws + 2 * XB_BYTES + (size_t)B_ * N_ * 8);
  unsigned* colmin = (unsigned*)(ws + 2 * XB_BYTES + (size_t)B_ * N_ * 12);

  prep_kernel<<<16384, 256, 0, stream>>>(gts, preds, Xb, Yb, xx, yy, rowmin, colmin,
                                         (float*)d_out);

  // 8 batches x 32 row-tiles x 4 col-quarters = 1024 blocks = 4/CU exactly
  chamfer_gemm<<<1024, 256, 0, stream>>>(Xb, Yb, xx, yy, rowmin, colmin);

  reduce_kernel<<<64, 256, 0, stream>>>(rowmin, (float*)d_out);
}